// Round 1
// baseline (544.434 us; speedup 1.0000x reference)
//
#include <hip/hip_runtime.h>

// ---------- types & helpers ----------
typedef __attribute__((ext_vector_type(8))) __bf16 bf16x8;
typedef __attribute__((ext_vector_type(4))) float f32x4;

#define DEVI __device__ __forceinline__

DEVI unsigned short f2bf(float f) {
    unsigned u = __builtin_bit_cast(unsigned, f);
    u += 0x7fffu + ((u >> 16) & 1u);
    return (unsigned short)(u >> 16);
}
DEVI float bf2f(unsigned short h) {
    unsigned u = ((unsigned)h) << 16;
    return __builtin_bit_cast(float, u);
}
DEVI float gelu_tanh(float x) {
    float u = 0.7978845608028654f * (x + 0.044715f * x * x * x);
    float t = 1.0f - 2.0f / (1.0f + __expf(2.0f * u));
    return 0.5f * x * (1.0f + t);
}
DEVI void gload16(const void* g, void* l) {
    __builtin_amdgcn_global_load_lds((const __attribute__((address_space(1))) unsigned int*)g,
                                     (__attribute__((address_space(3))) unsigned int*)l,
                                     16, 0, 0);
}

// problem constants
#define BB 8
#define SS 2048
#define DD 1024
#define EE 8
#define FF 2048
#define CC 320
#define NTOK (BB * SS)           // 16384
#define MPE (BB * CC)            // 2560 slots per expert
#define NSLOT (EE * MPE)         // 20480

// ---------- kernel 1: RMSNorm + gate logits + softmax/argmax ----------
__global__ __launch_bounds__(256) void k_rms_gate(
    const float* __restrict__ data, const float* __restrict__ gate_w,
    const float* __restrict__ rms_w, unsigned short* __restrict__ norm_bf,
    float* __restrict__ logits_out, float* __restrict__ maxprob, int* __restrict__ eidx_out)
{
    const int token = blockIdx.x;
    const int t = threadIdx.x;
    const float4 v = ((const float4*)(data + (size_t)token * DD))[t];
    float ss = v.x * v.x + v.y * v.y + v.z * v.z + v.w * v.w;
#pragma unroll
    for (int o = 32; o; o >>= 1) ss += __shfl_down(ss, o, 64);
    __shared__ float sred[4];
    __shared__ float slog[8];
    __shared__ float sacc[4][8];
    if ((t & 63) == 0) sred[t >> 6] = ss;
    __syncthreads();
    const float tot = sred[0] + sred[1] + sred[2] + sred[3];
    const float scale = rsqrtf(tot * (1.0f / 1024.0f) + 1e-6f);
    const float4 w = ((const float4*)rms_w)[t];
    float nn[4] = { v.x * scale * w.x, v.y * scale * w.y, v.z * scale * w.z, v.w * scale * w.w };
    ushort4 nb;
    nb.x = f2bf(nn[0]); nb.y = f2bf(nn[1]); nb.z = f2bf(nn[2]); nb.w = f2bf(nn[3]);
    ((ushort4*)(norm_bf + (size_t)token * DD))[t] = nb;

    float acc[8] = {0, 0, 0, 0, 0, 0, 0, 0};
    const float4* g = (const float4*)(gate_w + t * 32);  // rows t*4..t*4+3 of [D][8]
#pragma unroll
    for (int d = 0; d < 4; ++d) {
        float4 p = g[2 * d], q = g[2 * d + 1];
        acc[0] += nn[d] * p.x; acc[1] += nn[d] * p.y; acc[2] += nn[d] * p.z; acc[3] += nn[d] * p.w;
        acc[4] += nn[d] * q.x; acc[5] += nn[d] * q.y; acc[6] += nn[d] * q.z; acc[7] += nn[d] * q.w;
    }
#pragma unroll
    for (int e = 0; e < 8; ++e) {
#pragma unroll
        for (int o = 32; o; o >>= 1) acc[e] += __shfl_down(acc[e], o, 64);
    }
    if ((t & 63) == 0) {
#pragma unroll
        for (int e = 0; e < 8; ++e) sacc[t >> 6][e] = acc[e];
    }
    __syncthreads();
    if (t < 8) {
        float l = sacc[0][t] + sacc[1][t] + sacc[2][t] + sacc[3][t];
        logits_out[(size_t)token * 8 + t] = l;
        slog[t] = l;
    }
    __syncthreads();
    if (t == 0) {
        float m = slog[0]; int am = 0;
#pragma unroll
        for (int e = 1; e < 8; ++e) { if (slog[e] > m) { m = slog[e]; am = e; } }
        float s = 0.f;
#pragma unroll
        for (int e = 0; e < 8; ++e) s += __expf(slog[e] - m);
        maxprob[token] = 1.0f / s;
        eidx_out[token] = am;
    }
}

// ---------- kernel 2: routing scan (per batch) ----------
__global__ __launch_bounds__(256) void k_route(
    const int* __restrict__ eidx, int* __restrict__ pos_out,
    float* __restrict__ idxf_out, int* __restrict__ slot_token)
{
    const int b = blockIdx.x, t = threadIdx.x;
    // init this batch's slots to -1
    for (int i = t; i < EE * CC; i += 256) {
        int e = i / CC, c = i % CC;
        slot_token[e * MPE + b * CC + c] = -1;
    }
    const int base = b * SS + t * 8;
    int e8[8];
#pragma unroll
    for (int j = 0; j < 8; ++j) e8[j] = eidx[base + j];
    int cnt[8] = {0, 0, 0, 0, 0, 0, 0, 0};
#pragma unroll
    for (int j = 0; j < 8; ++j) {
#pragma unroll
        for (int q = 0; q < 8; ++q) cnt[q] += (e8[j] == q);
    }
    __shared__ int sc[8][256];
#pragma unroll
    for (int q = 0; q < 8; ++q) sc[q][t] = cnt[q];
    __syncthreads();
    for (int off = 1; off < 256; off <<= 1) {
        int v[8];
#pragma unroll
        for (int q = 0; q < 8; ++q) v[q] = (t >= off) ? sc[q][t - off] : 0;
        __syncthreads();
#pragma unroll
        for (int q = 0; q < 8; ++q) sc[q][t] += v[q];
        __syncthreads();
    }
    int run[8];
#pragma unroll
    for (int q = 0; q < 8; ++q) run[q] = (t == 0) ? 0 : sc[q][t - 1];
#pragma unroll
    for (int j = 0; j < 8; ++j) {
        const int e = e8[j];
        const int tok = base + j;
        int pos = 0;
#pragma unroll
        for (int q = 0; q < 8; ++q) if (q == e) { pos = run[q]; run[q]++; }
        const bool kept = pos < CC;
        pos_out[tok] = kept ? pos : CC;
        idxf_out[tok] = (float)(kept ? e : 0);
        if (kept) slot_token[e * MPE + b * CC + pos] = tok;
    }
}

// ---------- kernel 3: transpose+convert weights: src [E][R][C] f32 -> dst [E][C][R] bf16 ----------
__global__ __launch_bounds__(256) void k_transcvt(
    const float* __restrict__ src, unsigned short* __restrict__ dst,
    int R, int C, int tiles_r, int tiles_c)
{
    const int bid = blockIdx.x;
    const int tpe = tiles_r * tiles_c;
    const int e = bid / tpe, rem = bid % tpe;
    const int tr = rem / tiles_c, tc = rem % tiles_c;
    __shared__ float tile[32][33];
    const int t = threadIdx.x, c = t & 31, r0 = t >> 5;
    const float* s = src + (size_t)e * R * C;
#pragma unroll
    for (int i = 0; i < 4; ++i) {
        int r = r0 + i * 8;
        tile[r][c] = s[(size_t)(tr * 32 + r) * C + tc * 32 + c];
    }
    __syncthreads();
    unsigned short* d = dst + (size_t)e * C * R;
#pragma unroll
    for (int i = 0; i < 4; ++i) {
        int r = r0 + i * 8;
        d[(size_t)(tc * 32 + r) * R + tr * 32 + c] = f2bf(tile[c][r]);
    }
}

// ---------- kernel 4: gather kept tokens into dense per-expert X buffer ----------
__global__ __launch_bounds__(256) void k_gather(
    const unsigned short* __restrict__ norm_bf, const int* __restrict__ slot_token,
    unsigned short* __restrict__ Xbuf)
{
    const int slot = blockIdx.x;
    const int t = threadIdx.x;
    const int tok = slot_token[slot];
    ushort4* dst = (ushort4*)(Xbuf + (size_t)slot * DD);
    if (tok < 0) {
        ushort4 z; z.x = 0; z.y = 0; z.z = 0; z.w = 0;
        dst[t] = z;
    } else {
        dst[t] = ((const ushort4*)(norm_bf + (size_t)tok * DD))[t];
    }
}

// ---------- GEMM: C[M=2560/e][N] = A[e][M][K] * Bt[e][N][K]^T  (bf16 in, f32 acc) ----------
// MODE 0: epilogue gelu -> bf16 H.  MODE 1: epilogue scatter final = data + mp*y.
template <int MODE>
__global__ __launch_bounds__(256) void k_gemm(
    const unsigned short* __restrict__ A, const unsigned short* __restrict__ Bt,
    unsigned short* __restrict__ H, const int* __restrict__ slot_token,
    const float* __restrict__ maxprob, const float* __restrict__ data,
    float* __restrict__ outF, int K, int N)
{
    const int ntn = N >> 7;
    const int tpe = 20 * ntn;
    const int bid = blockIdx.x;
    const int e = bid / tpe, rem = bid % tpe;
    const int tm = rem / ntn, tn = rem % ntn;

    __shared__ __align__(16) unsigned short sm[17408];  // staging 2x128x64, epilogue 128x136
    unsigned short* lsA = sm;
    unsigned short* lsB = sm + 8192;

    const int tid = threadIdx.x;
    const int w = tid >> 6, L = tid & 63;
    const int wr = w >> 1, wc = w & 1;
    const int rr = L & 15, g = L >> 4;
    const int crow = L >> 3, csl = L & 7;
    const int ssl = csl ^ crow;  // xor-swizzled source slot

    const size_t Abase = ((size_t)e * MPE + (size_t)tm * 128) * (size_t)K;
    const size_t Bbase = ((size_t)e * N + (size_t)tn * 128) * (size_t)K;

    f32x4 acc[4][4];
#pragma unroll
    for (int m = 0; m < 4; ++m)
#pragma unroll
        for (int n = 0; n < 4; ++n) acc[m][n] = 0.f;

    const int KT = K >> 6;
    for (int kt = 0; kt < KT; ++kt) {
        const int k0 = kt << 6;
#pragma unroll
        for (int ch = 0; ch < 4; ++ch) {
            const int rowl = w * 32 + ch * 8 + crow;
            gload16(A + Abase + (size_t)rowl * K + (k0 + (ssl << 3)),
                    lsA + (w * 32 + ch * 8) * 64);
            gload16(Bt + Bbase + (size_t)rowl * K + (k0 + (ssl << 3)),
                    lsB + (w * 32 + ch * 8) * 64);
        }
        __syncthreads();
#pragma unroll
        for (int ks = 0; ks < 2; ++ks) {
            bf16x8 af[4], bfr[4];
#pragma unroll
            for (int m = 0; m < 4; ++m) {
                const int row = wr * 64 + m * 16 + rr;
                af[m] = *(const bf16x8*)(lsA + row * 64 + ((((ks << 2) | g) ^ (row & 7)) << 3));
            }
#pragma unroll
            for (int n = 0; n < 4; ++n) {
                const int row = wc * 64 + n * 16 + rr;
                bfr[n] = *(const bf16x8*)(lsB + row * 64 + ((((ks << 2) | g) ^ (row & 7)) << 3));
            }
#pragma unroll
            for (int m = 0; m < 4; ++m)
#pragma unroll
                for (int n = 0; n < 4; ++n)
                    acc[m][n] = __builtin_amdgcn_mfma_f32_16x16x32_bf16(af[m], bfr[n], acc[m][n], 0, 0, 0);
        }
        __syncthreads();
    }

    // epilogue: stage tile as bf16 in LDS [128][136], then coalesced copy-out
    unsigned short* lo = sm;
#pragma unroll
    for (int m = 0; m < 4; ++m)
#pragma unroll
        for (int n = 0; n < 4; ++n) {
            f32x4 a = acc[m][n];
            const int rl = wr * 64 + m * 16 + g * 4;
            const int cl = wc * 64 + n * 16 + rr;
#pragma unroll
            for (int j = 0; j < 4; ++j) {
                float x = a[j];
                if (MODE == 0) x = gelu_tanh(x);
                lo[(rl + j) * 136 + cl] = f2bf(x);
            }
        }
    __syncthreads();

    if (MODE == 0) {
        const size_t hrow0 = (size_t)e * MPE + (size_t)tm * 128;
#pragma unroll
        for (int i = 0; i < 8; ++i) {
            const int ch2 = tid + i * 256;
            const int row = ch2 >> 4, off = (ch2 & 15) << 3;
            int4 vv = *(const int4*)(lo + row * 136 + off);
            *(int4*)(H + (hrow0 + row) * 2048 + tn * 128 + off) = vv;
        }
    } else {
        const int slot0 = e * MPE + tm * 128;
#pragma unroll
        for (int i = 0; i < 8; ++i) {
            const int ch2 = tid + i * 256;
            const int row = ch2 >> 4, off = (ch2 & 15) << 3;
            const int tok = slot_token[slot0 + row];
            if (tok < 0) continue;
            const float mp = maxprob[tok];
            int4 yv = *(const int4*)(lo + row * 136 + off);
            const unsigned short* yy = (const unsigned short*)&yv;
            const size_t go = (size_t)tok * DD + (size_t)(tn * 128 + off);
            float4 d0 = *(const float4*)(data + go);
            float4 d1 = *(const float4*)(data + go + 4);
            float4 o0, o1;
            o0.x = d0.x + mp * bf2f(yy[0]);
            o0.y = d0.y + mp * bf2f(yy[1]);
            o0.z = d0.z + mp * bf2f(yy[2]);
            o0.w = d0.w + mp * bf2f(yy[3]);
            o1.x = d1.x + mp * bf2f(yy[4]);
            o1.y = d1.y + mp * bf2f(yy[5]);
            o1.z = d1.z + mp * bf2f(yy[6]);
            o1.w = d1.w + mp * bf2f(yy[7]);
            *(float4*)(outF + go) = o0;
            *(float4*)(outF + go + 4) = o1;
        }
    }
}

// ---------- kernel 7: dropped tokens: final = data + mp * norm ----------
__global__ __launch_bounds__(128) void k_fill(
    const int* __restrict__ pos, const float* __restrict__ maxprob,
    const unsigned short* __restrict__ norm_bf, const float* __restrict__ data,
    float* __restrict__ outF)
{
    const int tok = blockIdx.x;
    if (pos[tok] < CC) return;
    const float mp = maxprob[tok];
    const int t = threadIdx.x;
    const size_t o = (size_t)tok * DD + (size_t)t * 8;
    float4 d0 = *(const float4*)(data + o);
    float4 d1 = *(const float4*)(data + o + 4);
    ushort4 n0 = *(const ushort4*)(norm_bf + o);
    ushort4 n1 = *(const ushort4*)(norm_bf + o + 4);
    float4 r0, r1;
    r0.x = d0.x + mp * bf2f(n0.x);
    r0.y = d0.y + mp * bf2f(n0.y);
    r0.z = d0.z + mp * bf2f(n0.z);
    r0.w = d0.w + mp * bf2f(n0.w);
    r1.x = d1.x + mp * bf2f(n1.x);
    r1.y = d1.y + mp * bf2f(n1.y);
    r1.z = d1.z + mp * bf2f(n1.z);
    r1.w = d1.w + mp * bf2f(n1.w);
    *(float4*)(outF + o) = r0;
    *(float4*)(outF + o + 4) = r1;
}

// ---------- launch ----------
extern "C" void kernel_launch(void* const* d_in, const int* in_sizes, int n_in,
                              void* d_out, int out_size, void* d_ws, size_t ws_size,
                              hipStream_t stream)
{
    (void)in_sizes; (void)n_in; (void)out_size; (void)ws_size;
    const float* data   = (const float*)d_in[0];
    const float* gate_w = (const float*)d_in[1];
    const float* w1     = (const float*)d_in[2];
    const float* w2     = (const float*)d_in[3];
    const float* rms_w  = (const float*)d_in[4];

    float* outF   = (float*)d_out;
    float* logits = outF + (size_t)NTOK * DD;           // 16,777,216
    float* idxf   = logits + (size_t)NTOK * EE;          // +131,072

    char* ws = (char*)d_ws;
    const size_t SZ_NORM = (size_t)NTOK * DD * 2;        // 32 MB
    const size_t SZ_W1T  = (size_t)EE * DD * FF * 2;     // 32 MB
    const size_t SZ_W2T  = SZ_W1T;                       // 32 MB
    const size_t SZ_X    = (size_t)NSLOT * DD * 2;       // 40 MB
    const size_t SZ_H    = (size_t)NSLOT * FF * 2;       // 80 MB
    unsigned short* norm_bf = (unsigned short*)(ws);
    unsigned short* w1T     = (unsigned short*)(ws + SZ_NORM);
    unsigned short* w2T     = (unsigned short*)(ws + SZ_NORM + SZ_W1T);
    unsigned short* Xbuf    = (unsigned short*)(ws + SZ_NORM + SZ_W1T + SZ_W2T);
    unsigned short* Hbuf    = (unsigned short*)(ws + SZ_NORM + SZ_W1T + SZ_W2T + SZ_X);
    char* small             = ws + SZ_NORM + SZ_W1T + SZ_W2T + SZ_X + SZ_H;
    int*   slot_token = (int*)(small);
    int*   pos        = (int*)(small + NSLOT * 4);
    int*   eidx       = (int*)(small + NSLOT * 4 + NTOK * 4);
    float* maxprob    = (float*)(small + NSLOT * 4 + NTOK * 4 + NTOK * 4);

    k_rms_gate<<<NTOK, 256, 0, stream>>>(data, gate_w, rms_w, norm_bf, logits, maxprob, eidx);
    k_route<<<BB, 256, 0, stream>>>(eidx, pos, idxf, slot_token);
    k_transcvt<<<EE * 32 * 64, 256, 0, stream>>>(w1, w1T, DD, FF, 32, 64);   // -> [E][F][D]
    k_transcvt<<<EE * 64 * 32, 256, 0, stream>>>(w2, w2T, FF, DD, 64, 32);   // -> [E][D][F]
    k_gather<<<NSLOT, 256, 0, stream>>>(norm_bf, slot_token, Xbuf);
    k_gemm<0><<<EE * 20 * (FF / 128), 256, 0, stream>>>(Xbuf, w1T, Hbuf, nullptr, nullptr, nullptr, nullptr, DD, FF);
    k_gemm<1><<<EE * 20 * (DD / 128), 256, 0, stream>>>(Hbuf, w2T, nullptr, slot_token, maxprob, data, outF, FF, DD);
    k_fill<<<NTOK, 128, 0, stream>>>(pos, maxprob, norm_bf, data, outF);
}

// Round 3
// 522.012 us; speedup vs baseline: 1.0430x; 1.0430x over previous
//
#include <hip/hip_runtime.h>

// ---------- types & helpers ----------
typedef __attribute__((ext_vector_type(8))) __bf16 bf16x8;
typedef __attribute__((ext_vector_type(4))) float f32x4;

#define DEVI __device__ __forceinline__

DEVI unsigned short f2bf(float f) {
    unsigned u = __builtin_bit_cast(unsigned, f);
    u += 0x7fffu + ((u >> 16) & 1u);
    return (unsigned short)(u >> 16);
}
DEVI float bf2f(unsigned short h) {
    unsigned u = ((unsigned)h) << 16;
    return __builtin_bit_cast(float, u);
}
DEVI float gelu_tanh(float x) {
    float u = 0.7978845608028654f * (x + 0.044715f * x * x * x);
    float t = 1.0f - 2.0f / (1.0f + __expf(2.0f * u));
    return 0.5f * x * (1.0f + t);
}
DEVI void gload16(const void* g, void* l) {
    __builtin_amdgcn_global_load_lds((const __attribute__((address_space(1))) unsigned int*)g,
                                     (__attribute__((address_space(3))) unsigned int*)l,
                                     16, 0, 0);
}

// problem constants
#define BB 8
#define SS 2048
#define DD 1024
#define EE 8
#define FF 2048
#define CC 320
#define NTOK (BB * SS)           // 16384
#define MPE (BB * CC)            // 2560 slots per expert
#define NSLOT (EE * MPE)         // 20480

// ---------- kernel 1: RMSNorm + gate logits + softmax/argmax ----------
__global__ __launch_bounds__(256) void k_rms_gate(
    const float* __restrict__ data, const float* __restrict__ gate_w,
    const float* __restrict__ rms_w, unsigned short* __restrict__ norm_bf,
    float* __restrict__ logits_out, float* __restrict__ maxprob, int* __restrict__ eidx_out)
{
    const int token = blockIdx.x;
    const int t = threadIdx.x;
    const float4 v = ((const float4*)(data + (size_t)token * DD))[t];
    float ss = v.x * v.x + v.y * v.y + v.z * v.z + v.w * v.w;
#pragma unroll
    for (int o = 32; o; o >>= 1) ss += __shfl_down(ss, o, 64);
    __shared__ float sred[4];
    __shared__ float slog[8];
    __shared__ float sacc[4][8];
    if ((t & 63) == 0) sred[t >> 6] = ss;
    __syncthreads();
    const float tot = sred[0] + sred[1] + sred[2] + sred[3];
    const float scale = rsqrtf(tot * (1.0f / 1024.0f) + 1e-6f);
    const float4 w = ((const float4*)rms_w)[t];
    float nn[4] = { v.x * scale * w.x, v.y * scale * w.y, v.z * scale * w.z, v.w * scale * w.w };
    ushort4 nb;
    nb.x = f2bf(nn[0]); nb.y = f2bf(nn[1]); nb.z = f2bf(nn[2]); nb.w = f2bf(nn[3]);
    ((ushort4*)(norm_bf + (size_t)token * DD))[t] = nb;

    float acc[8] = {0, 0, 0, 0, 0, 0, 0, 0};
    const float4* g = (const float4*)(gate_w + t * 32);  // rows t*4..t*4+3 of [D][8]
#pragma unroll
    for (int d = 0; d < 4; ++d) {
        float4 p = g[2 * d], q = g[2 * d + 1];
        acc[0] += nn[d] * p.x; acc[1] += nn[d] * p.y; acc[2] += nn[d] * p.z; acc[3] += nn[d] * p.w;
        acc[4] += nn[d] * q.x; acc[5] += nn[d] * q.y; acc[6] += nn[d] * q.z; acc[7] += nn[d] * q.w;
    }
#pragma unroll
    for (int e = 0; e < 8; ++e) {
#pragma unroll
        for (int o = 32; o; o >>= 1) acc[e] += __shfl_down(acc[e], o, 64);
    }
    if ((t & 63) == 0) {
#pragma unroll
        for (int e = 0; e < 8; ++e) sacc[t >> 6][e] = acc[e];
    }
    __syncthreads();
    if (t < 8) {
        float l = sacc[0][t] + sacc[1][t] + sacc[2][t] + sacc[3][t];
        logits_out[(size_t)token * 8 + t] = l;
        slog[t] = l;
    }
    __syncthreads();
    if (t == 0) {
        float m = slog[0]; int am = 0;
#pragma unroll
        for (int e = 1; e < 8; ++e) { if (slog[e] > m) { m = slog[e]; am = e; } }
        float s = 0.f;
#pragma unroll
        for (int e = 0; e < 8; ++e) s += __expf(slog[e] - m);
        maxprob[token] = 1.0f / s;
        eidx_out[token] = am;
    }
}

// ---------- kernel 2: routing scan (per batch) + zero-page init ----------
__global__ __launch_bounds__(256) void k_route(
    const int* __restrict__ eidx, int* __restrict__ pos_out,
    float* __restrict__ idxf_out, int* __restrict__ slot_token, int* __restrict__ zp)
{
    const int b = blockIdx.x, t = threadIdx.x;
    if (b == 0) {  // zero the 2KB zero-page (bf16 zeros for empty-slot A rows)
        zp[t] = 0; zp[t + 256] = 0;
    }
    // init this batch's slots to -1
    for (int i = t; i < EE * CC; i += 256) {
        int e = i / CC, c = i % CC;
        slot_token[e * MPE + b * CC + c] = -1;
    }
    const int base = b * SS + t * 8;
    int e8[8];
#pragma unroll
    for (int j = 0; j < 8; ++j) e8[j] = eidx[base + j];
    int cnt[8] = {0, 0, 0, 0, 0, 0, 0, 0};
#pragma unroll
    for (int j = 0; j < 8; ++j) {
#pragma unroll
        for (int q = 0; q < 8; ++q) cnt[q] += (e8[j] == q);
    }
    __shared__ int sc[8][256];
#pragma unroll
    for (int q = 0; q < 8; ++q) sc[q][t] = cnt[q];
    __syncthreads();
    for (int off = 1; off < 256; off <<= 1) {
        int v[8];
#pragma unroll
        for (int q = 0; q < 8; ++q) v[q] = (t >= off) ? sc[q][t - off] : 0;
        __syncthreads();
#pragma unroll
        for (int q = 0; q < 8; ++q) sc[q][t] += v[q];
        __syncthreads();
    }
    int run[8];
#pragma unroll
    for (int q = 0; q < 8; ++q) run[q] = (t == 0) ? 0 : sc[q][t - 1];
#pragma unroll
    for (int j = 0; j < 8; ++j) {
        const int e = e8[j];
        const int tok = base + j;
        int pos = 0;
#pragma unroll
        for (int q = 0; q < 8; ++q) if (q == e) { pos = run[q]; run[q]++; }
        const bool kept = pos < CC;
        pos_out[tok] = kept ? pos : CC;
        idxf_out[tok] = (float)(kept ? e : 0);
        if (kept) slot_token[e * MPE + b * CC + pos] = tok;
    }
}

// ---------- kernel 3: transpose+convert BOTH weights in one launch ----------
// w1 [E][1024][2048] f32 -> w1T [E][2048][1024] bf16   (tiles: 32r x 64c per expert)
// w2 [E][2048][1024] f32 -> w2T [E][1024][2048] bf16   (tiles: 64r x 32c per expert)
DEVI void transcvt_tile(const float* __restrict__ src, unsigned short* __restrict__ dst,
                        int R, int C, int e, int tr, int tc, int t)
{
    __shared__ float tile[32][33];
    const int c = t & 31, r0 = t >> 5;
    const float* s = src + (size_t)e * R * C;
#pragma unroll
    for (int i = 0; i < 4; ++i) {
        int r = r0 + i * 8;
        tile[r][c] = s[(size_t)(tr * 32 + r) * C + tc * 32 + c];
    }
    __syncthreads();
    unsigned short* d = dst + (size_t)e * C * R;
#pragma unroll
    for (int i = 0; i < 4; ++i) {
        int r = r0 + i * 8;
        d[(size_t)(tc * 32 + r) * R + tr * 32 + c] = f2bf(tile[c][r]);
    }
}

__global__ __launch_bounds__(256) void k_transcvt2(
    const float* __restrict__ w1, const float* __restrict__ w2,
    unsigned short* __restrict__ w1T, unsigned short* __restrict__ w2T)
{
    const int bid = blockIdx.x;
    const int t = threadIdx.x;
    if (bid < EE * 32 * 64) {
        const int e = bid / (32 * 64), rem = bid % (32 * 64);
        transcvt_tile(w1, w1T, DD, FF, e, rem / 64, rem % 64, t);
    } else {
        const int b2 = bid - EE * 32 * 64;
        const int e = b2 / (64 * 32), rem = b2 % (64 * 32);
        transcvt_tile(w2, w2T, FF, DD, e, rem / 32, rem % 32, t);
    }
}

// ---------- GEMM: C[M=2560/e][N] = A[e][M][K] * Bt[e][N][K]^T  (bf16 in, f32 acc) ----------
// MODE 0: A gathered per-row from norm_bf via slot_token; epilogue gelu -> bf16 H.
// MODE 1: A dense (Hbuf);      epilogue scatter final = data + mp*y.
// XCD swizzle: bid&7 selects expert -> each expert's panel stays in one XCD's L2.
template <int MODE>
__global__ __launch_bounds__(256) void k_gemm(
    const unsigned short* __restrict__ A, const unsigned short* __restrict__ Bt,
    unsigned short* __restrict__ H, const int* __restrict__ slot_token,
    const float* __restrict__ maxprob, const float* __restrict__ data,
    float* __restrict__ outF, const unsigned short* __restrict__ zp, int K, int N)
{
    const int ntn = N >> 7;
    const int bid = blockIdx.x;
    const int e = bid & 7;           // expert == XCD (round-robin dispatch heuristic)
    const int inner = bid >> 3;      // [0, 20*ntn)
    const int tm = inner / ntn, tn = inner % ntn;

    __shared__ __align__(16) unsigned short sm[17408];  // staging 2x128x64, epilogue 128x136
    unsigned short* lsA = sm;
    unsigned short* lsB = sm + 8192;

    const int tid = threadIdx.x;
    const int w = tid >> 6, L = tid & 63;
    const int wr = w >> 1, wc = w & 1;
    const int rr = L & 15, g = L >> 4;
    const int crow = L >> 3, csl = L & 7;
    const int ssl = csl ^ crow;  // xor-swizzled source slot

    const int slot0 = e * MPE + tm * 128;
    const size_t Bbase = ((size_t)e * N + (size_t)tn * 128) * (size_t)K;

    // per-row source pointers (constant across K-loop)
    const unsigned short* aptr[4];
    const unsigned short* bptr[4];
#pragma unroll
    for (int ch = 0; ch < 4; ++ch) {
        const int rowl = w * 32 + ch * 8 + crow;
        if (MODE == 0) {
            const int tok = slot_token[slot0 + rowl];
            aptr[ch] = (tok < 0) ? zp : (A + (size_t)tok * DD);
        } else {
            aptr[ch] = A + ((size_t)slot0 + rowl) * (size_t)K;
        }
        bptr[ch] = Bt + Bbase + (size_t)rowl * K;
    }

    f32x4 acc[4][4];
#pragma unroll
    for (int m = 0; m < 4; ++m)
#pragma unroll
        for (int n = 0; n < 4; ++n) acc[m][n] = 0.f;

    const int KT = K >> 6;
    for (int kt = 0; kt < KT; ++kt) {
        const int koff = (kt << 6) + (ssl << 3);
#pragma unroll
        for (int ch = 0; ch < 4; ++ch) {
            gload16(aptr[ch] + koff, lsA + (w * 32 + ch * 8) * 64);
            gload16(bptr[ch] + koff, lsB + (w * 32 + ch * 8) * 64);
        }
        __syncthreads();
#pragma unroll
        for (int ks = 0; ks < 2; ++ks) {
            bf16x8 af[4], bfr[4];
#pragma unroll
            for (int m = 0; m < 4; ++m) {
                const int row = wr * 64 + m * 16 + rr;
                af[m] = *(const bf16x8*)(lsA + row * 64 + ((((ks << 2) | g) ^ (row & 7)) << 3));
            }
#pragma unroll
            for (int n = 0; n < 4; ++n) {
                const int row = wc * 64 + n * 16 + rr;
                bfr[n] = *(const bf16x8*)(lsB + row * 64 + ((((ks << 2) | g) ^ (row & 7)) << 3));
            }
#pragma unroll
            for (int m = 0; m < 4; ++m)
#pragma unroll
                for (int n = 0; n < 4; ++n)
                    acc[m][n] = __builtin_amdgcn_mfma_f32_16x16x32_bf16(af[m], bfr[n], acc[m][n], 0, 0, 0);
        }
        __syncthreads();
    }

    // epilogue: stage tile as bf16 in LDS [128][136], then coalesced copy-out
    unsigned short* lo = sm;
#pragma unroll
    for (int m = 0; m < 4; ++m)
#pragma unroll
        for (int n = 0; n < 4; ++n) {
            f32x4 a = acc[m][n];
            const int rl = wr * 64 + m * 16 + g * 4;
            const int cl = wc * 64 + n * 16 + rr;
#pragma unroll
            for (int j = 0; j < 4; ++j) {
                float x = a[j];
                if (MODE == 0) x = gelu_tanh(x);
                lo[(rl + j) * 136 + cl] = f2bf(x);
            }
        }
    __syncthreads();

    if (MODE == 0) {
        const size_t hrow0 = (size_t)slot0;
#pragma unroll
        for (int i = 0; i < 8; ++i) {
            const int ch2 = tid + i * 256;
            const int row = ch2 >> 4, off = (ch2 & 15) << 3;
            int4 vv = *(const int4*)(lo + row * 136 + off);
            *(int4*)(H + (hrow0 + row) * 2048 + tn * 128 + off) = vv;
        }
    } else {
#pragma unroll
        for (int i = 0; i < 8; ++i) {
            const int ch2 = tid + i * 256;
            const int row = ch2 >> 4, off = (ch2 & 15) << 3;
            const int tok = slot_token[slot0 + row];
            if (tok < 0) continue;
            const float mp = maxprob[tok];
            int4 yv = *(const int4*)(lo + row * 136 + off);
            const unsigned short* yy = (const unsigned short*)&yv;
            const size_t go = (size_t)tok * DD + (size_t)(tn * 128 + off);
            float4 d0 = *(const float4*)(data + go);
            float4 d1 = *(const float4*)(data + go + 4);
            float4 o0, o1;
            o0.x = d0.x + mp * bf2f(yy[0]);
            o0.y = d0.y + mp * bf2f(yy[1]);
            o0.z = d0.z + mp * bf2f(yy[2]);
            o0.w = d0.w + mp * bf2f(yy[3]);
            o1.x = d1.x + mp * bf2f(yy[4]);
            o1.y = d1.y + mp * bf2f(yy[5]);
            o1.z = d1.z + mp * bf2f(yy[6]);
            o1.w = d1.w + mp * bf2f(yy[7]);
            *(float4*)(outF + go) = o0;
            *(float4*)(outF + go + 4) = o1;
        }
    }
}

// ---------- kernel 7: dropped tokens: final = data + mp * norm ----------
__global__ __launch_bounds__(128) void k_fill(
    const int* __restrict__ pos, const float* __restrict__ maxprob,
    const unsigned short* __restrict__ norm_bf, const float* __restrict__ data,
    float* __restrict__ outF)
{
    const int tok = blockIdx.x;
    if (pos[tok] < CC) return;
    const float mp = maxprob[tok];
    const int t = threadIdx.x;
    const size_t o = (size_t)tok * DD + (size_t)t * 8;
    float4 d0 = *(const float4*)(data + o);
    float4 d1 = *(const float4*)(data + o + 4);
    ushort4 n0 = *(const ushort4*)(norm_bf + o);
    ushort4 n1 = *(const ushort4*)(norm_bf + o + 4);
    float4 r0, r1;
    r0.x = d0.x + mp * bf2f(n0.x);
    r0.y = d0.y + mp * bf2f(n0.y);
    r0.z = d0.z + mp * bf2f(n0.z);
    r0.w = d0.w + mp * bf2f(n0.w);
    r1.x = d1.x + mp * bf2f(n1.x);
    r1.y = d1.y + mp * bf2f(n1.y);
    r1.z = d1.z + mp * bf2f(n1.z);
    r1.w = d1.w + mp * bf2f(n1.w);
    *(float4*)(outF + o) = r0;
    *(float4*)(outF + o + 4) = r1;
}

// ---------- launch ----------
extern "C" void kernel_launch(void* const* d_in, const int* in_sizes, int n_in,
                              void* d_out, int out_size, void* d_ws, size_t ws_size,
                              hipStream_t stream)
{
    (void)in_sizes; (void)n_in; (void)out_size; (void)ws_size;
    const float* data   = (const float*)d_in[0];
    const float* gate_w = (const float*)d_in[1];
    const float* w1     = (const float*)d_in[2];
    const float* w2     = (const float*)d_in[3];
    const float* rms_w  = (const float*)d_in[4];

    float* outF   = (float*)d_out;
    float* logits = outF + (size_t)NTOK * DD;           // 16,777,216
    float* idxf   = logits + (size_t)NTOK * EE;          // +131,072

    char* ws = (char*)d_ws;
    const size_t SZ_NORM = (size_t)NTOK * DD * 2;        // 32 MB
    const size_t SZ_W1T  = (size_t)EE * DD * FF * 2;     // 32 MB
    const size_t SZ_W2T  = SZ_W1T;                       // 32 MB
    const size_t SZ_H    = (size_t)NSLOT * FF * 2;       // 80 MB
    unsigned short* norm_bf = (unsigned short*)(ws);
    unsigned short* w1T     = (unsigned short*)(ws + SZ_NORM);
    unsigned short* w2T     = (unsigned short*)(ws + SZ_NORM + SZ_W1T);
    unsigned short* Hbuf    = (unsigned short*)(ws + SZ_NORM + SZ_W1T + SZ_W2T);
    char* small             = ws + SZ_NORM + SZ_W1T + SZ_W2T + SZ_H;
    int*   slot_token = (int*)(small);
    int*   pos        = (int*)(small + NSLOT * 4);
    int*   eidx       = (int*)(small + NSLOT * 4 + NTOK * 4);
    float* maxprob    = (float*)(small + NSLOT * 4 + NTOK * 4 + NTOK * 4);
    int*   zp         = (int*)(small + NSLOT * 4 + NTOK * 4 + NTOK * 4 + NTOK * 4);

    k_rms_gate<<<NTOK, 256, 0, stream>>>(data, gate_w, rms_w, norm_bf, logits, maxprob, eidx);
    k_route<<<BB, 256, 0, stream>>>(eidx, pos, idxf, slot_token, zp);
    k_transcvt2<<<EE * 32 * 64 * 2, 256, 0, stream>>>(w1, w2, w1T, w2T);
    k_gemm<0><<<EE * 20 * (FF / 128), 256, 0, stream>>>(norm_bf, w1T, Hbuf, slot_token, nullptr, nullptr, nullptr, (const unsigned short*)zp, DD, FF);
    k_gemm<1><<<EE * 20 * (DD / 128), 256, 0, stream>>>(Hbuf, w2T, nullptr, slot_token, maxprob, data, outF, nullptr, FF, DD);
    k_fill<<<NTOK, 128, 0, stream>>>(pos, maxprob, norm_bf, data, outF);
}